// Round 1
// baseline (872.564 us; speedup 1.0000x reference)
//
#include <hip/hip_runtime.h>
#include <math.h>

#define N_ROWS 1048576
#define H 128
#define B 128
#define NEG_SLOPE 0.01f

#define GRID_MAIN 1024
#define ROWS_PB (N_ROWS / GRID_MAIN)   // 1024 rows per block
#define ITERS (ROWS_PB / 8)            // 8 half-waves per 256-thread block

// ---------- float <-> order-preserving uint (for atomicMax on floats) ----------
__device__ __forceinline__ unsigned ford(float f) {
    unsigned u = __float_as_uint(f);
    return (u & 0x80000000u) ? ~u : (u | 0x80000000u);
}
__device__ __forceinline__ float funord(unsigned u) {
    u = (u & 0x80000000u) ? (u & 0x7FFFFFFFu) : ~u;
    return __uint_as_float(u);
}

// ---------- init: zero accumulators ----------
__global__ void init_kernel(unsigned* __restrict__ m_ord,
                            float* __restrict__ denom,
                            float* __restrict__ numer) {
    int tid = blockIdx.x * blockDim.x + threadIdx.x;
    if (tid < B * H) numer[tid] = 0.0f;
    if (tid < B) { m_ord[tid] = 0u; denom[tid] = 0.0f; }  // 0 < ford(-inf), safe identity
}

// ---------- q_score[b] = dot(attention_query[b], w_q) ----------
__global__ __launch_bounds__(256) void qs_kernel(const float* __restrict__ aq,
                                                 const float* __restrict__ w,
                                                 float* __restrict__ qs) {
    const int lane = threadIdx.x & 63;
    const int wave = threadIdx.x >> 6;
    const int half = lane >> 5;
    const int hl   = lane & 31;
    const int b    = blockIdx.x * 8 + wave * 2 + half;   // grid 16 x 256 -> 128
    float4 w4 = ((const float4*)(w + H))[hl];
    float4 a4 = ((const float4*)(aq + (long)b * H))[hl];
    float d = a4.x * w4.x + a4.y * w4.y + a4.z * w4.z + a4.w * w4.w;
    #pragma unroll
    for (int off = 1; off < 32; off <<= 1) d += __shfl_xor(d, off, 32);
    if (hl == 0) qs[b] = d;
}

// ---------- pass 1: gate + per-segment max ----------
__global__ __launch_bounds__(256) void gate_kernel(const float* __restrict__ h,
                                                   const int* __restrict__ seg,
                                                   const float* __restrict__ w,
                                                   const float* __restrict__ qs,
                                                   float* __restrict__ gate,
                                                   unsigned* __restrict__ m_ord) {
    const int lane = threadIdx.x & 63;
    const int wave = threadIdx.x >> 6;
    const int half = lane >> 5;
    const int hl   = lane & 31;
    const int hwid = wave * 2 + half;                    // 0..7
    const long r0  = (long)blockIdx.x * ROWS_PB;

    float4 w4 = ((const float4*)w)[hl];                  // w_h fragment

    int   cur_seg = -1;
    float cur_max = 0.0f;

    for (int it = 0; it < ITERS; ++it) {
        long row = r0 + hwid + (long)it * 8;
        float4 h4 = ((const float4*)(h + row * H))[hl];
        float d = h4.x * w4.x + h4.y * w4.y + h4.z * w4.z + h4.w * w4.w;
        #pragma unroll
        for (int off = 1; off < 32; off <<= 1) d += __shfl_xor(d, off, 32);
        int s = seg[row];
        float g = d + qs[s];
        g = (g >= 0.0f) ? g : NEG_SLOPE * g;
        if (hl == 0) gate[row] = g;
        if (s != cur_seg) {
            if (cur_seg >= 0 && hl == 0) atomicMax(m_ord + cur_seg, ford(cur_max));
            cur_seg = s;
            cur_max = g;
        } else {
            cur_max = fmaxf(cur_max, g);
        }
    }
    if (cur_seg >= 0 && hl == 0) atomicMax(m_ord + cur_seg, ford(cur_max));
}

// ---------- pass 2: e = exp(gate - m), accumulate numer & denom ----------
__global__ __launch_bounds__(256) void accum_kernel(const float* __restrict__ h,
                                                    const int* __restrict__ seg,
                                                    const float* __restrict__ gate,
                                                    const unsigned* __restrict__ m_ord,
                                                    float* __restrict__ denom,
                                                    float* __restrict__ numer) {
    const int lane = threadIdx.x & 63;
    const int wave = threadIdx.x >> 6;
    const int half = lane >> 5;
    const int hl   = lane & 31;
    const int hwid = wave * 2 + half;
    const long r0  = (long)blockIdx.x * ROWS_PB;

    int    cur_seg = -1;
    float  mcur = 0.0f;
    float4 acc  = {0.0f, 0.0f, 0.0f, 0.0f};
    float  accd = 0.0f;

    for (int it = 0; it < ITERS; ++it) {
        long row = r0 + hwid + (long)it * 8;
        int s = seg[row];
        if (s != cur_seg) {
            if (cur_seg >= 0) {
                float* dst = numer + (long)cur_seg * H + hl * 4;
                atomicAdd(dst + 0, acc.x);
                atomicAdd(dst + 1, acc.y);
                atomicAdd(dst + 2, acc.z);
                atomicAdd(dst + 3, acc.w);
                if (hl == 0) atomicAdd(denom + cur_seg, accd);
            }
            cur_seg = s;
            mcur = funord(m_ord[s]);
            acc = make_float4(0.0f, 0.0f, 0.0f, 0.0f);
            accd = 0.0f;
        }
        float e = __expf(gate[row] - mcur);
        float4 h4 = ((const float4*)(h + row * H))[hl];
        acc.x += e * h4.x;
        acc.y += e * h4.y;
        acc.z += e * h4.z;
        acc.w += e * h4.w;
        accd += e;
    }
    if (cur_seg >= 0) {
        float* dst = numer + (long)cur_seg * H + hl * 4;
        atomicAdd(dst + 0, acc.x);
        atomicAdd(dst + 1, acc.y);
        atomicAdd(dst + 2, acc.z);
        atomicAdd(dst + 3, acc.w);
        if (hl == 0) atomicAdd(denom + cur_seg, accd);
    }
}

// ---------- finalize: out = numer / max(denom, 1e-20) ----------
__global__ void finalize_kernel(const float* __restrict__ numer,
                                const float* __restrict__ denom,
                                float* __restrict__ out) {
    int tid = blockIdx.x * blockDim.x + threadIdx.x;
    if (tid < B * H) {
        float d = denom[tid >> 7];   // tid / H
        out[tid] = numer[tid] / fmaxf(d, 1e-20f);
    }
}

extern "C" void kernel_launch(void* const* d_in, const int* in_sizes, int n_in,
                              void* d_out, int out_size, void* d_ws, size_t ws_size,
                              hipStream_t stream) {
    const float* h   = (const float*)d_in[0];   // (N, H)
    const float* aq  = (const float*)d_in[1];   // (B, H)
    const float* w   = (const float*)d_in[2];   // (2H,)
    const int*   seg = (const int*)d_in[3];     // (N,) sorted
    float* out = (float*)d_out;                 // (B, H)

    // ws layout (floats): gate[N] | m_ord[B] (as uint) | denom[B] | qs[B] | numer[B*H]
    float*    ws    = (float*)d_ws;
    float*    gate  = ws;
    unsigned* m_ord = (unsigned*)(ws + N_ROWS);
    float*    denom = ws + N_ROWS + B;
    float*    qs    = ws + N_ROWS + 2 * B;
    float*    numer = ws + N_ROWS + 3 * B;

    init_kernel<<<(B * H + 255) / 256, 256, 0, stream>>>(m_ord, denom, numer);
    qs_kernel<<<16, 256, 0, stream>>>(aq, w, qs);
    gate_kernel<<<GRID_MAIN, 256, 0, stream>>>(h, seg, w, qs, gate, m_ord);
    accum_kernel<<<GRID_MAIN, 256, 0, stream>>>(h, seg, gate, m_ord, denom, numer);
    finalize_kernel<<<(B * H + 255) / 256, 256, 0, stream>>>(numer, denom, out);
}

// Round 2
// 764.840 us; speedup vs baseline: 1.1408x; 1.1408x over previous
//
#include <hip/hip_runtime.h>
#include <math.h>

#define N_ROWS 1048576
#define H 128
#define B 128
#define NEG_SLOPE 0.01f

#define GRID_MAIN 2048
#define ROWS_PB (N_ROWS / GRID_MAIN)      // 512 rows per block
#define ITERS (ROWS_PB / 16)              // 32 iters; 8 half-waves x 2 rows/iter
#define MAXP 256                          // partial slots per segment (worst case ~150)

// ---------- qs = aq @ w_q (one dot per segment) + zero the slot counters ----------
__global__ __launch_bounds__(256) void qs_init_kernel(const float* __restrict__ aq,
                                                      const float* __restrict__ w,
                                                      float* __restrict__ qs,
                                                      int* __restrict__ counter) {
    if (blockIdx.x == 0 && threadIdx.x < B) counter[threadIdx.x] = 0;
    const int lane = threadIdx.x & 63;
    const int wave = threadIdx.x >> 6;
    const int half = lane >> 5;
    const int hl   = lane & 31;
    const int b    = blockIdx.x * 8 + wave * 2 + half;   // grid 16 x 256 -> 128
    float4 w4 = ((const float4*)(w + H))[hl];
    float4 a4 = ((const float4*)(aq + (long)b * H))[hl];
    float d = a4.x * w4.x + a4.y * w4.y + a4.z * w4.z + a4.w * w4.w;
    #pragma unroll
    for (int off = 1; off < 32; off <<= 1) d += __shfl_xor(d, off, 32);
    if (hl == 0) qs[b] = d;
}

// ---------- single pass: gate + online softmax + partial flush ----------
__global__ __launch_bounds__(256) void main_kernel(const float* __restrict__ h,
                                                   const int* __restrict__ seg,
                                                   const float* __restrict__ w,
                                                   const float* __restrict__ qs,
                                                   int* __restrict__ counter,
                                                   float* __restrict__ pm,
                                                   float* __restrict__ pd,
                                                   float* __restrict__ pacc) {
    __shared__ float qs_s[B];
    if (threadIdx.x < B) qs_s[threadIdx.x] = qs[threadIdx.x];
    __syncthreads();

    const int lane = threadIdx.x & 63;
    const int wave = threadIdx.x >> 6;
    const int half = lane >> 5;
    const int hl   = lane & 31;
    const int hwid = wave * 2 + half;                    // 0..7
    const long r0  = (long)blockIdx.x * ROWS_PB;

    float4 w4 = ((const float4*)w)[hl];                  // w_h fragment

    int    cur   = -1;
    float  m_run = -1e30f;
    float  d_run = 0.0f;
    float4 acc   = {0.0f, 0.0f, 0.0f, 0.0f};

    for (int it = 0; it < ITERS; ++it) {
        long r1 = r0 + hwid + (long)it * 16;
        long r2 = r1 + 8;
        // issue all global loads up front (MLP)
        float4 ha = ((const float4*)(h + r1 * H))[hl];
        float4 hb = ((const float4*)(h + r2 * H))[hl];
        int s1 = seg[r1];
        int s2 = seg[r2];

        #pragma unroll
        for (int k = 0; k < 2; ++k) {
            float4 h4 = k ? hb : ha;
            int    s  = k ? s2 : s1;
            float d = h4.x * w4.x + h4.y * w4.y + h4.z * w4.z + h4.w * w4.w;
            #pragma unroll
            for (int off = 1; off < 32; off <<= 1) d += __shfl_xor(d, off, 32);
            float g = d + qs_s[s];
            g = (g >= 0.0f) ? g : NEG_SLOPE * g;

            if (s != cur) {                              // half-wave-uniform branch
                if (cur >= 0) {                          // flush partial
                    int slot = 0;
                    if (hl == 0) slot = atomicAdd(counter + cur, 1);
                    slot = __shfl(slot, 0, 32);
                    slot = min(slot, MAXP - 1);
                    long base = (long)cur * MAXP + slot;
                    ((float4*)(pacc + base * H))[hl] = acc;
                    if (hl == 0) { pm[base] = m_run; pd[base] = d_run; }
                }
                cur = s;
                m_run = -1e30f;
                d_run = 0.0f;
                acc = make_float4(0.0f, 0.0f, 0.0f, 0.0f);
            }
            float m_new = fmaxf(m_run, g);
            float sc = __expf(m_run - m_new);            // 1.0 if no new max; 0 on first row
            float e  = __expf(g - m_new);
            acc.x = acc.x * sc + e * h4.x;
            acc.y = acc.y * sc + e * h4.y;
            acc.z = acc.z * sc + e * h4.z;
            acc.w = acc.w * sc + e * h4.w;
            d_run = d_run * sc + e;
            m_run = m_new;
        }
    }
    if (cur >= 0) {                                      // final flush
        int slot = 0;
        if (hl == 0) slot = atomicAdd(counter + cur, 1);
        slot = __shfl(slot, 0, 32);
        slot = min(slot, MAXP - 1);
        long base = (long)cur * MAXP + slot;
        ((float4*)(pacc + base * H))[hl] = acc;
        if (hl == 0) { pm[base] = m_run; pd[base] = d_run; }
    }
}

// ---------- merge partials per segment, divide, write out ----------
__global__ __launch_bounds__(128) void merge_kernel(const int* __restrict__ counter,
                                                    const float* __restrict__ pm,
                                                    const float* __restrict__ pd,
                                                    const float* __restrict__ pacc,
                                                    float* __restrict__ out) {
    const int s = blockIdx.x;
    const int t = threadIdx.x;                           // 0..127 = H column
    const int c = min(counter[s], MAXP);
    const long sb = (long)s * MAXP;

    float M = -1e30f;
    for (int j = 0; j < c; ++j) M = fmaxf(M, pm[sb + j]);

    float D = 0.0f, a = 0.0f;
    for (int j = 0; j < c; ++j) {
        float sc = __expf(pm[sb + j] - M);
        D += pd[sb + j] * sc;
        a += pacc[(sb + j) * H + t] * sc;
    }
    out[s * H + t] = (c > 0) ? a / fmaxf(D, 1e-20f) : 0.0f;
}

extern "C" void kernel_launch(void* const* d_in, const int* in_sizes, int n_in,
                              void* d_out, int out_size, void* d_ws, size_t ws_size,
                              hipStream_t stream) {
    const float* h   = (const float*)d_in[0];   // (N, H)
    const float* aq  = (const float*)d_in[1];   // (B, H)
    const float* w   = (const float*)d_in[2];   // (2H,)
    const int*   seg = (const int*)d_in[3];     // (N,) sorted
    float* out = (float*)d_out;                 // (B, H)

    // ws layout (floats): qs[B] | counter[B] (int) | pm[B*MAXP] | pd[B*MAXP] | pacc[B*MAXP*H]
    float* ws      = (float*)d_ws;
    float* qs      = ws;
    int*   counter = (int*)(ws + B);
    float* pm      = ws + 2 * B;
    float* pd      = ws + 2 * B + B * MAXP;
    float* pacc    = ws + 2 * B + 2 * B * MAXP;   // 16B-aligned (offset 263168 bytes)

    qs_init_kernel<<<16, 256, 0, stream>>>(aq, w, qs, counter);
    main_kernel<<<GRID_MAIN, 256, 0, stream>>>(h, seg, w, qs, counter, pm, pd, pacc);
    merge_kernel<<<B, 128, 0, stream>>>(counter, pm, pd, pacc, out);
}

// Round 3
// 702.956 us; speedup vs baseline: 1.2413x; 1.0880x over previous
//
#include <hip/hip_runtime.h>
#include <math.h>

#define N_ROWS 1048576
#define H 128
#define B 128
#define NEG_SLOPE 0.01f

#define GRID_MAIN 2048
#define ROWS_PB (N_ROWS / GRID_MAIN)      // 512 rows per block
#define MAXP 256                          // partial slots per segment

__device__ __forceinline__ float dot4(float4 a, float4 b) {
    return a.x * b.x + a.y * b.y + a.z * b.z + a.w * b.w;
}

// ---------- qs = aq @ w_q (one dot per segment) + zero the slot counters ----------
__global__ __launch_bounds__(256) void qs_init_kernel(const float* __restrict__ aq,
                                                      const float* __restrict__ w,
                                                      float* __restrict__ qs,
                                                      int* __restrict__ counter) {
    if (blockIdx.x == 0 && threadIdx.x < B) counter[threadIdx.x] = 0;
    const int lane = threadIdx.x & 63;
    const int wave = threadIdx.x >> 6;
    const int half = lane >> 5;
    const int hl   = lane & 31;
    const int b    = blockIdx.x * 8 + wave * 2 + half;   // grid 16 x 256 -> 128
    float4 w4 = ((const float4*)(w + H))[hl];
    float4 a4 = ((const float4*)(aq + (long)b * H))[hl];
    float d = dot4(a4, w4);
    #pragma unroll
    for (int off = 1; off < 32; off <<= 1) d += __shfl_xor(d, off, 32);
    if (hl == 0) qs[b] = d;
}

// ---------- single pass: gate + online softmax + partial flush ----------
__global__ __launch_bounds__(256) void main_kernel(const float* __restrict__ h,
                                                   const int* __restrict__ seg,
                                                   const float* __restrict__ w,
                                                   const float* __restrict__ qs,
                                                   int* __restrict__ counter,
                                                   float* __restrict__ pm,
                                                   float* __restrict__ pd,
                                                   float* __restrict__ pacc) {
    __shared__ float qs_s[B];
    if (threadIdx.x < B) qs_s[threadIdx.x] = qs[threadIdx.x];
    __syncthreads();

    const int lane = threadIdx.x & 63;
    const int wave = threadIdx.x >> 6;
    const int half = lane >> 5;
    const int hl   = lane & 31;
    const int hwid = wave * 2 + half;                    // 0..7
    const long r0  = (long)blockIdx.x * ROWS_PB;

    float4 w4 = ((const float4*)w)[hl];                  // w_h fragment

    const int sFirst = seg[r0];
    const int sLast  = seg[r0 + ROWS_PB - 1];

    if (sFirst == sLast) {
        // ---------------- FAST PATH: whole block in one segment ----------------
        const float qsv = qs_s[sFirst];
        float  m_run = -1e30f;
        float  d_run = 0.0f;
        float4 acc   = {0.0f, 0.0f, 0.0f, 0.0f};

        for (int it = 0; it < ROWS_PB / 32; ++it) {      // 16 iters, 4 rows/half-wave
            long rb = r0 + hwid + (long)it * 32;
            float4 h0 = ((const float4*)(h + rb * H))[hl];
            float4 h1 = ((const float4*)(h + (rb + 8)  * H))[hl];
            float4 h2 = ((const float4*)(h + (rb + 16) * H))[hl];
            float4 h3 = ((const float4*)(h + (rb + 24) * H))[hl];

            float d0 = dot4(h0, w4), d1 = dot4(h1, w4);
            float d2 = dot4(h2, w4), d3 = dot4(h3, w4);
            #pragma unroll
            for (int off = 1; off < 32; off <<= 1) {     // 4 independent chains (ILP)
                d0 += __shfl_xor(d0, off, 32);
                d1 += __shfl_xor(d1, off, 32);
                d2 += __shfl_xor(d2, off, 32);
                d3 += __shfl_xor(d3, off, 32);
            }
            float g0 = d0 + qsv; g0 = (g0 >= 0.0f) ? g0 : NEG_SLOPE * g0;
            float g1 = d1 + qsv; g1 = (g1 >= 0.0f) ? g1 : NEG_SLOPE * g1;
            float g2 = d2 + qsv; g2 = (g2 >= 0.0f) ? g2 : NEG_SLOPE * g2;
            float g3 = d3 + qsv; g3 = (g3 >= 0.0f) ? g3 : NEG_SLOPE * g3;

            #pragma unroll
            for (int u = 0; u < 4; ++u) {
                float  g  = (u == 0) ? g0 : (u == 1) ? g1 : (u == 2) ? g2 : g3;
                float4 hv = (u == 0) ? h0 : (u == 1) ? h1 : (u == 2) ? h2 : h3;
                float mn = fmaxf(m_run, g);
                float sc = __expf(m_run - mn);
                float e  = __expf(g - mn);
                acc.x = acc.x * sc + e * hv.x;
                acc.y = acc.y * sc + e * hv.y;
                acc.z = acc.z * sc + e * hv.z;
                acc.w = acc.w * sc + e * hv.w;
                d_run = d_run * sc + e;
                m_run = mn;
            }
        }
        // cross-half merge -> one partial per wave
        float m_o = __shfl_xor(m_run, 32);
        float d_o = __shfl_xor(d_run, 32);
        float4 a_o;
        a_o.x = __shfl_xor(acc.x, 32);
        a_o.y = __shfl_xor(acc.y, 32);
        a_o.z = __shfl_xor(acc.z, 32);
        a_o.w = __shfl_xor(acc.w, 32);
        float M  = fmaxf(m_run, m_o);
        float ss = __expf(m_run - M);
        float so = __expf(m_o  - M);
        float4 am;
        am.x = acc.x * ss + a_o.x * so;
        am.y = acc.y * ss + a_o.y * so;
        am.z = acc.z * ss + a_o.z * so;
        am.w = acc.w * ss + a_o.w * so;
        float Dm = d_run * ss + d_o * so;

        int slot = 0;
        if (lane == 0) slot = atomicAdd(counter + sFirst, 1);
        slot = min(__shfl(slot, 0), MAXP - 1);
        long base = (long)sFirst * MAXP + slot;
        if (half == 0) ((float4*)(pacc + base * H))[hl] = am;
        if (lane == 0) { pm[base] = M; pd[base] = Dm; }
    } else {
        // ---------------- SLOW PATH: block crosses segment boundary ----------------
        int    cur   = -1;
        float  m_run = -1e30f;
        float  d_run = 0.0f;
        float4 acc   = {0.0f, 0.0f, 0.0f, 0.0f};

        for (int it = 0; it < ROWS_PB / 16; ++it) {      // 32 iters, 2 rows/half-wave
            long r1 = r0 + hwid + (long)it * 16;
            long r2 = r1 + 8;
            float4 ha = ((const float4*)(h + r1 * H))[hl];
            float4 hb = ((const float4*)(h + r2 * H))[hl];
            int s1 = seg[r1];
            int s2 = seg[r2];

            #pragma unroll
            for (int k = 0; k < 2; ++k) {
                float4 h4 = k ? hb : ha;
                int    s  = k ? s2 : s1;
                float d = dot4(h4, w4);
                #pragma unroll
                for (int off = 1; off < 32; off <<= 1) d += __shfl_xor(d, off, 32);
                float g = d + qs_s[s];
                g = (g >= 0.0f) ? g : NEG_SLOPE * g;

                if (s != cur) {                          // half-wave-uniform branch
                    if (cur >= 0) {
                        int slot = 0;
                        if (hl == 0) slot = atomicAdd(counter + cur, 1);
                        slot = min(__shfl(slot, 0, 32), MAXP - 1);
                        long base = (long)cur * MAXP + slot;
                        ((float4*)(pacc + base * H))[hl] = acc;
                        if (hl == 0) { pm[base] = m_run; pd[base] = d_run; }
                    }
                    cur = s;
                    m_run = -1e30f;
                    d_run = 0.0f;
                    acc = make_float4(0.0f, 0.0f, 0.0f, 0.0f);
                }
                float mn = fmaxf(m_run, g);
                float sc = __expf(m_run - mn);
                float e  = __expf(g - mn);
                acc.x = acc.x * sc + e * h4.x;
                acc.y = acc.y * sc + e * h4.y;
                acc.z = acc.z * sc + e * h4.z;
                acc.w = acc.w * sc + e * h4.w;
                d_run = d_run * sc + e;
                m_run = mn;
            }
        }
        if (cur >= 0) {
            int slot = 0;
            if (hl == 0) slot = atomicAdd(counter + cur, 1);
            slot = min(__shfl(slot, 0, 32), MAXP - 1);
            long base = (long)cur * MAXP + slot;
            ((float4*)(pacc + base * H))[hl] = acc;
            if (hl == 0) { pm[base] = m_run; pd[base] = d_run; }
        }
    }
}

// ---------- merge partials per segment (parallelized), divide, write out ----------
__global__ __launch_bounds__(128) void merge_kernel(const int* __restrict__ counter,
                                                    const float* __restrict__ pm,
                                                    const float* __restrict__ pd,
                                                    const float* __restrict__ pacc,
                                                    float* __restrict__ out) {
    const int s = blockIdx.x;
    const int t = threadIdx.x;                           // 0..127 = H column
    const int c = min(counter[s], MAXP);
    const long sb = (long)s * MAXP;

    __shared__ float red[2];
    __shared__ float scv[MAXP];

    // phase 1: segment max over partials (parallel + shuffle reduce)
    float lm = -1e30f;
    for (int j = t; j < c; j += 128) lm = fmaxf(lm, pm[sb + j]);
    #pragma unroll
    for (int off = 1; off < 64; off <<= 1) lm = fmaxf(lm, __shfl_xor(lm, off));
    if ((t & 63) == 0) red[t >> 6] = lm;
    __syncthreads();
    float M = fmaxf(red[0], red[1]);
    __syncthreads();                                     // protect red reuse

    // phase 2a: scales to LDS + denom reduce
    float ld = 0.0f;
    for (int j = t; j < c; j += 128) {
        float sc = __expf(pm[sb + j] - M);
        scv[j] = sc;
        ld += pd[sb + j] * sc;
    }
    #pragma unroll
    for (int off = 1; off < 64; off <<= 1) ld += __shfl_xor(ld, off);
    if ((t & 63) == 0) red[t >> 6] = ld;
    __syncthreads();
    float D = red[0] + red[1];

    // phase 2b: weighted accumulation (coalesced, unrolled)
    float a = 0.0f;
    #pragma unroll 4
    for (int j = 0; j < c; ++j) a += pacc[(sb + j) * H + t] * scv[j];

    out[s * H + t] = (c > 0) ? a / fmaxf(D, 1e-20f) : 0.0f;
}

extern "C" void kernel_launch(void* const* d_in, const int* in_sizes, int n_in,
                              void* d_out, int out_size, void* d_ws, size_t ws_size,
                              hipStream_t stream) {
    const float* h   = (const float*)d_in[0];   // (N, H)
    const float* aq  = (const float*)d_in[1];   // (B, H)
    const float* w   = (const float*)d_in[2];   // (2H,)
    const int*   seg = (const int*)d_in[3];     // (N,) sorted
    float* out = (float*)d_out;                 // (B, H)

    // ws layout (floats): qs[B] | counter[B] (int) | pm[B*MAXP] | pd[B*MAXP] | pacc[B*MAXP*H]
    float* ws      = (float*)d_ws;
    float* qs      = ws;
    int*   counter = (int*)(ws + B);
    float* pm      = ws + 2 * B;
    float* pd      = ws + 2 * B + B * MAXP;
    float* pacc    = ws + 2 * B + 2 * B * MAXP;   // 16B-aligned (offset 263168 bytes)

    qs_init_kernel<<<16, 256, 0, stream>>>(aq, w, qs, counter);
    main_kernel<<<GRID_MAIN, 256, 0, stream>>>(h, seg, w, qs, counter, pm, pd, pacc);
    merge_kernel<<<B, 128, 0, stream>>>(counter, pm, pd, pacc, out);
}

// Round 4
// 701.825 us; speedup vs baseline: 1.2433x; 1.0016x over previous
//
#include <hip/hip_runtime.h>
#include <math.h>

#define N_ROWS 1048576
#define H 128
#define B 128
#define NEG_SLOPE 0.01f

#define GRID_MAIN 2048
#define ROWS_PB (N_ROWS / GRID_MAIN)      // 512 rows per block
#define MAXP 256                          // partial slots per segment

__device__ __forceinline__ float dot4(float4 a, float4 b) {
    return a.x * b.x + a.y * b.y + a.z * b.z + a.w * b.w;
}

// ---------- qs = aq @ w_q (one dot per segment) + zero the slot counters ----------
__global__ __launch_bounds__(256) void qs_init_kernel(const float* __restrict__ aq,
                                                      const float* __restrict__ w,
                                                      float* __restrict__ qs,
                                                      int* __restrict__ counter) {
    if (blockIdx.x == 0 && threadIdx.x < B) counter[threadIdx.x] = 0;
    const int lane = threadIdx.x & 63;
    const int wave = threadIdx.x >> 6;
    const int half = lane >> 5;
    const int hl   = lane & 31;
    const int b    = blockIdx.x * 8 + wave * 2 + half;   // grid 16 x 256 -> 128
    float4 w4 = ((const float4*)(w + H))[hl];
    float4 a4 = ((const float4*)(aq + (long)b * H))[hl];
    float d = dot4(a4, w4);
    #pragma unroll
    for (int off = 1; off < 32; off <<= 1) d += __shfl_xor(d, off, 32);
    if (hl == 0) qs[b] = d;
}

// ---------- single pass: gate + online softmax + partial flush ----------
__global__ __launch_bounds__(256) void main_kernel(const float* __restrict__ h,
                                                   const int* __restrict__ seg,
                                                   const float* __restrict__ w,
                                                   const float* __restrict__ qs,
                                                   int* __restrict__ counter,
                                                   float* __restrict__ pm,
                                                   float* __restrict__ pd,
                                                   float* __restrict__ pacc) {
    __shared__ float qs_s[B];
    if (threadIdx.x < B) qs_s[threadIdx.x] = qs[threadIdx.x];
    __syncthreads();

    const int lane = threadIdx.x & 63;
    const int wave = threadIdx.x >> 6;
    const int half = lane >> 5;
    const int hl   = lane & 31;
    const int hwid = wave * 2 + half;                    // 0..7
    const long r0  = (long)blockIdx.x * ROWS_PB;

    float4 w4 = ((const float4*)w)[hl];                  // w_h fragment

    const int sFirst = seg[r0];
    const int sLast  = seg[r0 + ROWS_PB - 1];

    if (sFirst == sLast) {
        // ---------------- FAST PATH: whole block in one segment ----------------
        const float qsv = qs_s[sFirst];
        float  m_run = -1e30f;
        float  d_run = 0.0f;
        float4 acc   = {0.0f, 0.0f, 0.0f, 0.0f};

        for (int it = 0; it < ROWS_PB / 32; ++it) {      // 16 iters, 4 consecutive rows/half-wave
            long base = r0 + (long)it * 32 + hwid * 4;
            const float4* hp = (const float4*)(h + base * H) + hl;
            float4 h0 = hp[0];                           // row base   (128 f = 32 float4)
            float4 h1 = hp[32];                          // row base+1
            float4 h2 = hp[64];                          // row base+2
            float4 h3 = hp[96];                          // row base+3

            float d0 = dot4(h0, w4), d1 = dot4(h1, w4);
            float d2 = dot4(h2, w4), d3 = dot4(h3, w4);

            // packed butterfly: 13 shuffles for 4 row-sums + broadcast (vs 20)
            float s0 = d0 + __shfl_xor(d0, 16, 32);
            float s1 = d1 + __shfl_xor(d1, 16, 32);
            float s2 = d2 + __shfl_xor(d2, 16, 32);
            float s3 = d3 + __shfl_xor(d3, 16, 32);
            float z01 = (hl & 16) ? s1 : s0;             // rows 0|1 in lane halves
            float z23 = (hl & 16) ? s3 : s2;             // rows 2|3
            float t01 = z01 + __shfl_xor(z01, 8, 32);
            float t23 = z23 + __shfl_xor(z23, 8, 32);
            float zz  = (hl & 8) ? t23 : t01;            // rows 0,2,1,3 in 8-lane groups
            zz += __shfl_xor(zz, 4, 32);
            zz += __shfl_xor(zz, 2, 32);
            zz += __shfl_xor(zz, 1, 32);
            float g0 = __shfl(zz,  0, 32) + qsv;
            float g1 = __shfl(zz, 16, 32) + qsv;
            float g2 = __shfl(zz,  8, 32) + qsv;
            float g3 = __shfl(zz, 24, 32) + qsv;
            g0 = (g0 >= 0.0f) ? g0 : NEG_SLOPE * g0;
            g1 = (g1 >= 0.0f) ? g1 : NEG_SLOPE * g1;
            g2 = (g2 >= 0.0f) ? g2 : NEG_SLOPE * g2;
            g3 = (g3 >= 0.0f) ? g3 : NEG_SLOPE * g3;

            #pragma unroll
            for (int u = 0; u < 4; ++u) {
                float  g  = (u == 0) ? g0 : (u == 1) ? g1 : (u == 2) ? g2 : g3;
                float4 hv = (u == 0) ? h0 : (u == 1) ? h1 : (u == 2) ? h2 : h3;
                if (g <= m_run) {                        // common path (uniform per half)
                    float e = __expf(g - m_run);
                    acc.x += e * hv.x;
                    acc.y += e * hv.y;
                    acc.z += e * hv.z;
                    acc.w += e * hv.w;
                    d_run += e;
                } else {                                 // rare: new max (e == 1)
                    float sc = __expf(m_run - g);        // exp(-inf)=0 on first row
                    acc.x = acc.x * sc + hv.x;
                    acc.y = acc.y * sc + hv.y;
                    acc.z = acc.z * sc + hv.z;
                    acc.w = acc.w * sc + hv.w;
                    d_run = d_run * sc + 1.0f;
                    m_run = g;
                }
            }
        }
        // cross-half merge -> one partial per wave
        float m_o = __shfl_xor(m_run, 32);
        float d_o = __shfl_xor(d_run, 32);
        float4 a_o;
        a_o.x = __shfl_xor(acc.x, 32);
        a_o.y = __shfl_xor(acc.y, 32);
        a_o.z = __shfl_xor(acc.z, 32);
        a_o.w = __shfl_xor(acc.w, 32);
        float M  = fmaxf(m_run, m_o);
        float ss = __expf(m_run - M);
        float so = __expf(m_o  - M);
        float4 am;
        am.x = acc.x * ss + a_o.x * so;
        am.y = acc.y * ss + a_o.y * so;
        am.z = acc.z * ss + a_o.z * so;
        am.w = acc.w * ss + a_o.w * so;
        float Dm = d_run * ss + d_o * so;

        int slot = 0;
        if (lane == 0) slot = atomicAdd(counter + sFirst, 1);
        slot = min(__shfl(slot, 0), MAXP - 1);
        long pbase = (long)sFirst * MAXP + slot;
        if (half == 0) ((float4*)(pacc + pbase * H))[hl] = am;
        if (lane == 0) { pm[pbase] = M; pd[pbase] = Dm; }
    } else {
        // ---------------- SLOW PATH: block crosses segment boundary ----------------
        int    cur   = -1;
        float  m_run = -1e30f;
        float  d_run = 0.0f;
        float4 acc   = {0.0f, 0.0f, 0.0f, 0.0f};

        for (int it = 0; it < ROWS_PB / 16; ++it) {      // 32 iters, 2 rows/half-wave
            long r1 = r0 + hwid + (long)it * 16;
            long r2 = r1 + 8;
            float4 ha = ((const float4*)(h + r1 * H))[hl];
            float4 hb = ((const float4*)(h + r2 * H))[hl];
            int s1 = seg[r1];
            int s2 = seg[r2];

            #pragma unroll
            for (int k = 0; k < 2; ++k) {
                float4 h4 = k ? hb : ha;
                int    s  = k ? s2 : s1;
                float d = dot4(h4, w4);
                #pragma unroll
                for (int off = 1; off < 32; off <<= 1) d += __shfl_xor(d, off, 32);
                float g = d + qs_s[s];
                g = (g >= 0.0f) ? g : NEG_SLOPE * g;

                if (s != cur) {                          // half-wave-uniform branch
                    if (cur >= 0) {
                        int slot = 0;
                        if (hl == 0) slot = atomicAdd(counter + cur, 1);
                        slot = min(__shfl(slot, 0, 32), MAXP - 1);
                        long pbase = (long)cur * MAXP + slot;
                        ((float4*)(pacc + pbase * H))[hl] = acc;
                        if (hl == 0) { pm[pbase] = m_run; pd[pbase] = d_run; }
                    }
                    cur = s;
                    m_run = -1e30f;
                    d_run = 0.0f;
                    acc = make_float4(0.0f, 0.0f, 0.0f, 0.0f);
                }
                if (g <= m_run) {
                    float e = __expf(g - m_run);
                    acc.x += e * h4.x;
                    acc.y += e * h4.y;
                    acc.z += e * h4.z;
                    acc.w += e * h4.w;
                    d_run += e;
                } else {
                    float sc = __expf(m_run - g);
                    acc.x = acc.x * sc + h4.x;
                    acc.y = acc.y * sc + h4.y;
                    acc.z = acc.z * sc + h4.z;
                    acc.w = acc.w * sc + h4.w;
                    d_run = d_run * sc + 1.0f;
                    m_run = g;
                }
            }
        }
        if (cur >= 0) {
            int slot = 0;
            if (hl == 0) slot = atomicAdd(counter + cur, 1);
            slot = min(__shfl(slot, 0, 32), MAXP - 1);
            long pbase = (long)cur * MAXP + slot;
            ((float4*)(pacc + pbase * H))[hl] = acc;
            if (hl == 0) { pm[pbase] = m_run; pd[pbase] = d_run; }
        }
    }
}

// ---------- merge partials per segment (parallelized), divide, write out ----------
__global__ __launch_bounds__(128) void merge_kernel(const int* __restrict__ counter,
                                                    const float* __restrict__ pm,
                                                    const float* __restrict__ pd,
                                                    const float* __restrict__ pacc,
                                                    float* __restrict__ out) {
    const int s = blockIdx.x;
    const int t = threadIdx.x;                           // 0..127 = H column
    const int c = min(counter[s], MAXP);
    const long sb = (long)s * MAXP;

    __shared__ float red[2];
    __shared__ float scv[MAXP];

    // phase 1: segment max over partials
    float lm = -1e30f;
    for (int j = t; j < c; j += 128) lm = fmaxf(lm, pm[sb + j]);
    #pragma unroll
    for (int off = 1; off < 64; off <<= 1) lm = fmaxf(lm, __shfl_xor(lm, off));
    if ((t & 63) == 0) red[t >> 6] = lm;
    __syncthreads();
    float M = fmaxf(red[0], red[1]);
    __syncthreads();

    // phase 2a: scales to LDS + denom reduce
    float ld = 0.0f;
    for (int j = t; j < c; j += 128) {
        float sc = __expf(pm[sb + j] - M);
        scv[j] = sc;
        ld += pd[sb + j] * sc;
    }
    #pragma unroll
    for (int off = 1; off < 64; off <<= 1) ld += __shfl_xor(ld, off);
    if ((t & 63) == 0) red[t >> 6] = ld;
    __syncthreads();
    float D = red[0] + red[1];

    // phase 2b: weighted accumulation (coalesced)
    float a = 0.0f;
    #pragma unroll 4
    for (int j = 0; j < c; ++j) a += pacc[(sb + j) * H + t] * scv[j];

    out[s * H + t] = (c > 0) ? a / fmaxf(D, 1e-20f) : 0.0f;
}

extern "C" void kernel_launch(void* const* d_in, const int* in_sizes, int n_in,
                              void* d_out, int out_size, void* d_ws, size_t ws_size,
                              hipStream_t stream) {
    const float* h   = (const float*)d_in[0];   // (N, H)
    const float* aq  = (const float*)d_in[1];   // (B, H)
    const float* w   = (const float*)d_in[2];   // (2H,)
    const int*   seg = (const int*)d_in[3];     // (N,) sorted
    float* out = (float*)d_out;                 // (B, H)

    // ws layout (floats): qs[B] | counter[B] (int) | pm[B*MAXP] | pd[B*MAXP] | pacc[B*MAXP*H]
    float* ws      = (float*)d_ws;
    float* qs      = ws;
    int*   counter = (int*)(ws + B);
    float* pm      = ws + 2 * B;
    float* pd      = ws + 2 * B + B * MAXP;
    float* pacc    = ws + 2 * B + 2 * B * MAXP;   // 16B-aligned

    qs_init_kernel<<<16, 256, 0, stream>>>(aq, w, qs, counter);
    main_kernel<<<GRID_MAIN, 256, 0, stream>>>(h, seg, w, qs, counter, pm, pd, pacc);
    merge_kernel<<<B, 128, 0, stream>>>(counter, pm, pd, pacc, out);
}